// Round 7
// baseline (170.355 us; speedup 1.0000x reference)
//
#include <hip/hip_runtime.h>
#include <math.h>

#define DIM     512
#define NNODES  10000
#define NEDGES  200000
#define MPAD    10048   // 157 * 64
#define NMB     157     // m-groups of 64

using short8  = __attribute__((ext_vector_type(8))) short;
using floatx4 = __attribute__((ext_vector_type(4))) float;
using half8   = __attribute__((ext_vector_type(8))) _Float16;

__device__ inline unsigned short f32_to_bf16_rn(float x) {
    unsigned u = __float_as_uint(x);
    unsigned r = (u + 0x7FFF + ((u >> 16) & 1)) >> 16;
    return (unsigned short)r;
}
__device__ inline float bf16_to_f32(unsigned short h) {
    return __uint_as_float(((unsigned)h) << 16);
}

// ---------------------------------------------------------------------------
// split_w: W (fp32 [k][n]) -> Wht, Wlt (bf16 [n][k]) via LDS tile transpose.
// Grid 64 blocks (8 kb x 8 nb), 256 threads. Also zeroes counts.
// ---------------------------------------------------------------------------
__global__ __launch_bounds__(256) void split_w(const float* __restrict__ W,
                                               unsigned short* __restrict__ Wht,
                                               unsigned short* __restrict__ Wlt,
                                               int* __restrict__ counts) {
    __shared__ float tile[64][65];
    const int tg = blockIdx.x * 256 + threadIdx.x;
    if (tg < NNODES) counts[tg] = 0;

    const int kb = (blockIdx.x >> 3) * 64;
    const int nb = (blockIdx.x & 7) * 64;
    const int kk = threadIdx.x >> 2;
    const int ch = threadIdx.x & 3;

    // read 16 consecutive floats of row kb+kk (coalesced)
    const float* src = W + (size_t)(kb + kk) * DIM + nb + ch * 16;
    #pragma unroll
    for (int q = 0; q < 4; ++q) {
        float4 v = *(const float4*)(src + q * 4);
        tile[kk][ch * 16 + q * 4 + 0] = v.x;
        tile[kk][ch * 16 + q * 4 + 1] = v.y;
        tile[kk][ch * 16 + q * 4 + 2] = v.z;
        tile[kk][ch * 16 + q * 4 + 3] = v.w;
    }
    __syncthreads();

    const int nn = kk;   // output row within tile
    unsigned short hi[16], lo[16];
    #pragma unroll
    for (int i = 0; i < 16; ++i) {
        float x = tile[ch * 16 + i][nn];
        unsigned short h = f32_to_bf16_rn(x);
        hi[i] = h;
        lo[i] = f32_to_bf16_rn(x - bf16_to_f32(h));
    }
    unsigned short* dh = Wht + (size_t)(nb + nn) * DIM + kb + ch * 16;
    unsigned short* dl = Wlt + (size_t)(nb + nn) * DIM + kb + ch * 16;
    *(short8*)(dh)     = *(short8*)&hi[0];
    *(short8*)(dh + 8) = *(short8*)&hi[8];
    *(short8*)(dl)     = *(short8*)&lo[0];
    *(short8*)(dl + 8) = *(short8*)&lo[8];
}

// ---------------------------------------------------------------------------
// GEMM v5: fused-split MFMA. Block = 64m x 128n, BK=32, 16 steps, grid 628.
// A: fp32 Z -> regs -> bf16 hi/lo ds_write, padded stride 40 shorts.
// B: Wht/Wlt via global_load_lds, DOUBLE-buffered; prefetch issued right
//    after the barrier so it flies across the whole MFMA phase.
// n_idx==0 blocks also emit the fp16 edge table Zh16.
// ---------------------------------------------------------------------------
__global__ __launch_bounds__(256) void gemm_mfma(const float* __restrict__ Z,
                                                 const unsigned short* __restrict__ Wht,
                                                 const unsigned short* __restrict__ Wlt,
                                                 float* __restrict__ ZW,
                                                 _Float16* __restrict__ Zh16) {
    __shared__ unsigned short Ahi[64 * 40];
    __shared__ unsigned short Alo[64 * 40];
    __shared__ unsigned short Bhi[2][128 * 32];
    __shared__ unsigned short Blo[2][128 * 32];

    const int t     = threadIdx.x;
    const int bid   = blockIdx.x;
    const int n_idx = bid & 3;
    const int m0    = (bid >> 2) * 64;
    const int n0    = n_idx * 128;

    const int l  = t & 63;
    const int w  = t >> 6;
    const int wn = w * 32;
    const int lm = l & 15;
    const int lq = l >> 4;

    const int arow = t >> 2;
    const int asub = t & 3;
    const bool avalid = (m0 + arow) < NNODES;
    const float* Abase = Z + (size_t)(m0 + arow) * DIM + asub * 8;

    floatx4 acc[4][2] = {};

    auto stageB = [&](int buf, int k0) {
        #pragma unroll
        for (int p = 0; p < 2; ++p) {
            const int s   = p * 256 + t;
            const int row = s >> 2;
            const int ch  = s & 3;
            const unsigned short* srcH = Wht + (size_t)(n0 + row) * DIM + k0 + ch * 8;
            const unsigned short* srcL = Wlt + (size_t)(n0 + row) * DIM + k0 + ch * 8;
            __builtin_amdgcn_global_load_lds(
                (const __attribute__((address_space(1))) void*)srcH,
                (__attribute__((address_space(3))) void*)&Bhi[buf][(p * 256 + (t & 192)) * 8],
                16, 0, 0);
            __builtin_amdgcn_global_load_lds(
                (const __attribute__((address_space(1))) void*)srcL,
                (__attribute__((address_space(3))) void*)&Blo[buf][(p * 256 + (t & 192)) * 8],
                16, 0, 0);
        }
    };

    float4 a0r = make_float4(0.f, 0.f, 0.f, 0.f), a1r = a0r;
    auto loadA = [&](int k0) {
        if (avalid) {
            a0r = *(const float4*)(Abase + k0);
            a1r = *(const float4*)(Abase + k0 + 4);
        } else {
            a0r = make_float4(0.f, 0.f, 0.f, 0.f);
            a1r = a0r;
        }
    };

    // prepare A LDS (and Zh16) for chunk k0 from current regs
    auto writeA = [&](int k0) {
        float x[8] = {a0r.x, a0r.y, a0r.z, a0r.w, a1r.x, a1r.y, a1r.z, a1r.w};
        short8 h8, l8;
        half8 f16;
        #pragma unroll
        for (int j = 0; j < 8; ++j) {
            unsigned short h = f32_to_bf16_rn(x[j]);
            h8[j] = (short)h;
            l8[j] = (short)f32_to_bf16_rn(x[j] - bf16_to_f32(h));
            f16[j] = (_Float16)x[j];
        }
        *(short8*)&Ahi[arow * 40 + asub * 8] = h8;
        *(short8*)&Alo[arow * 40 + asub * 8] = l8;
        if (n_idx == 0)
            *(half8*)(Zh16 + (size_t)(m0 + arow) * DIM + k0 + asub * 8) = f16;
    };

    loadA(0);
    writeA(0);
    stageB(0, 0);

    for (int s = 0; s < 16; ++s) {
        const int buf = s & 1;
        const int k0n = ((s + 1) & 15) * 32;

        __syncthreads();                       // drain B glds (buf) + A ds_writes
        if (s < 15) stageB(buf ^ 1, k0n);      // flies across the MFMA phase
        if (s < 15) loadA(k0n);                // register prefetch

        short8 aH[4], aL[4], bH[2], bL[2];
        #pragma unroll
        for (int i = 0; i < 4; ++i) {
            aH[i] = *(const short8*)&Ahi[(16 * i + lm) * 40 + lq * 8];
            aL[i] = *(const short8*)&Alo[(16 * i + lm) * 40 + lq * 8];
        }
        #pragma unroll
        for (int j = 0; j < 2; ++j) {
            bH[j] = *(const short8*)&Bhi[buf][(wn + 16 * j + lm) * 32 + lq * 8];
            bL[j] = *(const short8*)&Blo[buf][(wn + 16 * j + lm) * 32 + lq * 8];
        }
        #pragma unroll
        for (int i = 0; i < 4; ++i)
            #pragma unroll
            for (int j = 0; j < 2; ++j)
                acc[i][j] = __builtin_amdgcn_mfma_f32_16x16x32_bf16(aH[i], bH[j], acc[i][j], 0, 0, 0);
        #pragma unroll
        for (int i = 0; i < 4; ++i)
            #pragma unroll
            for (int j = 0; j < 2; ++j)
                acc[i][j] = __builtin_amdgcn_mfma_f32_16x16x32_bf16(aH[i], bL[j], acc[i][j], 0, 0, 0);
        #pragma unroll
        for (int i = 0; i < 4; ++i)
            #pragma unroll
            for (int j = 0; j < 2; ++j)
                acc[i][j] = __builtin_amdgcn_mfma_f32_16x16x32_bf16(aL[i], bH[j], acc[i][j], 0, 0, 0);

        __syncthreads();                       // WAR guard for A LDS
        if (s < 15) writeA(k0n);               // fast ds_writes for next step
    }

    #pragma unroll
    for (int i = 0; i < 4; ++i)
        #pragma unroll
        for (int j = 0; j < 2; ++j)
            #pragma unroll
            for (int r = 0; r < 4; ++r) {
                const int gm = m0 + 16 * i + lq * 4 + r;
                const int gn = n0 + wn + 16 * j + lm;
                if (gm < NNODES)
                    ZW[(size_t)gm * DIM + gn] = acc[i][j][r];
            }
}

// ---------------------------------------------------------------------------
// fp32 GEMM fallback (ws too small)
// ---------------------------------------------------------------------------
#define GTM 128
#define GTN 64
#define GTK 16
#define LDA 132
#define LDB 68

__global__ __launch_bounds__(256) void gemm_zw(const float* __restrict__ A,
                                               const float* __restrict__ B,
                                               float* __restrict__ C) {
    __shared__ float As[GTK * LDA];
    __shared__ float Bs[GTK * LDB];

    const int t  = threadIdx.x;
    const int m0 = blockIdx.x * GTM;
    const int n0 = blockIdx.y * GTN;
    const int tx = t & 15;
    const int ty = t >> 4;

    float acc[8][4] = {};

    for (int k0 = 0; k0 < DIM; k0 += GTK) {
        #pragma unroll
        for (int p = 0; p < 2; ++p) {
            int f  = t + p * 256;
            int mm = f >> 2;
            int kq = f & 3;
            int m  = m0 + mm;
            float4 v = make_float4(0.f, 0.f, 0.f, 0.f);
            if (m < NNODES)
                v = *(const float4*)(A + (size_t)m * DIM + k0 + kq * 4);
            As[(kq * 4 + 0) * LDA + mm] = v.x;
            As[(kq * 4 + 1) * LDA + mm] = v.y;
            As[(kq * 4 + 2) * LDA + mm] = v.z;
            As[(kq * 4 + 3) * LDA + mm] = v.w;
        }
        {
            int kb = t >> 4, n4 = t & 15;
            *(float4*)&Bs[kb * LDB + n4 * 4] =
                *(const float4*)(B + (size_t)(k0 + kb) * DIM + n0 + n4 * 4);
        }
        __syncthreads();

        #pragma unroll
        for (int kk = 0; kk < GTK; ++kk) {
            float4 a0 = *(const float4*)&As[kk * LDA + ty * 8];
            float4 a1 = *(const float4*)&As[kk * LDA + ty * 8 + 4];
            float4 b  = *(const float4*)&Bs[kk * LDB + tx * 4];
            float av[8] = {a0.x, a0.y, a0.z, a0.w, a1.x, a1.y, a1.z, a1.w};
            float bv[4] = {b.x, b.y, b.z, b.w};
            #pragma unroll
            for (int i = 0; i < 8; ++i)
                #pragma unroll
                for (int j = 0; j < 4; ++j)
                    acc[i][j] = fmaf(av[i], bv[j], acc[i][j]);
        }
        __syncthreads();
    }

    #pragma unroll
    for (int i = 0; i < 8; ++i) {
        int m = m0 + ty * 8 + i;
        if (m < NNODES)
            *(float4*)(C + (size_t)m * DIM + n0 + tx * 4) =
                make_float4(acc[i][0], acc[i][1], acc[i][2], acc[i][3]);
    }
}

// ---------------------------------------------------------------------------
// Counting sort of edges by row
// ---------------------------------------------------------------------------
__global__ void hist_rows(const int* __restrict__ eidx, int* __restrict__ counts) {
    int e = blockIdx.x * blockDim.x + threadIdx.x;
    if (e < NEDGES) atomicAdd(&counts[eidx[e]], 1);
}

__global__ __launch_bounds__(1024) void scan_counts(const int* __restrict__ counts,
                                                    int* __restrict__ offs,
                                                    int* __restrict__ cursor) {
    __shared__ int wsum[16];
    __shared__ int woff[17];
    const int t    = threadIdx.x;
    const int lane = t & 63;
    const int wv   = t >> 6;

    int local[10];
    int s = 0;
    if (t < 1000) {
        #pragma unroll
        for (int j = 0; j < 10; ++j) {
            local[j] = counts[t * 10 + j];
            s += local[j];
        }
    }
    int v = s;
    #pragma unroll
    for (int off = 1; off < 64; off <<= 1) {
        int u = __shfl_up(v, off, 64);
        if (lane >= off) v += u;
    }
    if (lane == 63) wsum[wv] = v;
    __syncthreads();
    if (t == 0) {
        int r = 0;
        #pragma unroll
        for (int i = 0; i < 16; ++i) { woff[i] = r; r += wsum[i]; }
        woff[16] = r;
    }
    __syncthreads();
    if (t < 1000) {
        int run = woff[wv] + (v - s);
        #pragma unroll
        for (int j = 0; j < 10; ++j) {
            offs[t * 10 + j]   = run;
            cursor[t * 10 + j] = run;
            run += local[j];
        }
    }
    if (t == 0) offs[NNODES] = woff[16];
}

__global__ void scatter_edges(const int* __restrict__ eidx,
                              int* __restrict__ cursor,
                              unsigned* __restrict__ keys) {
    int e = blockIdx.x * blockDim.x + threadIdx.x;
    if (e < NEDGES) {
        int r = eidx[e];
        int c = eidx[NEDGES + e];
        int pos = atomicAdd(&cursor[r], 1);
        keys[pos] = ((unsigned)c << 18) | (unsigned)e;
    }
}

// ---------------------------------------------------------------------------
// Edge scoring: one wave per row bucket; ZW row in regs; fp16 col gather.
// ---------------------------------------------------------------------------
__global__ __launch_bounds__(64) void edge_score_h(const float* __restrict__ ZW,
                                                   const _Float16* __restrict__ Zh,
                                                   const unsigned* __restrict__ keys,
                                                   const int* __restrict__ offs,
                                                   float* __restrict__ out) {
    const int r = blockIdx.x;
    const int start = offs[r];
    const int end   = offs[r + 1];
    if (start == end) return;

    const int lane = threadIdx.x;
    const float4 a0 = *(const float4*)(ZW + (size_t)r * DIM + lane * 8);
    const float4 a1 = *(const float4*)(ZW + (size_t)r * DIM + lane * 8 + 4);
    const float a[8] = {a0.x, a0.y, a0.z, a0.w, a1.x, a1.y, a1.z, a1.w};

    int i = start;
    for (; i + 3 < end; i += 4) {
        unsigned k0 = keys[i], k1 = keys[i + 1], k2 = keys[i + 2], k3 = keys[i + 3];
        half8 h0 = *(const half8*)(Zh + (size_t)(k0 >> 18) * DIM + lane * 8);
        half8 h1 = *(const half8*)(Zh + (size_t)(k1 >> 18) * DIM + lane * 8);
        half8 h2 = *(const half8*)(Zh + (size_t)(k2 >> 18) * DIM + lane * 8);
        half8 h3 = *(const half8*)(Zh + (size_t)(k3 >> 18) * DIM + lane * 8);

        float s0 = a[0] * (float)h0[0], s1 = a[0] * (float)h1[0];
        float s2 = a[0] * (float)h2[0], s3 = a[0] * (float)h3[0];
        #pragma unroll
        for (int j = 1; j < 8; ++j) {
            s0 = fmaf(a[j], (float)h0[j], s0);
            s1 = fmaf(a[j], (float)h1[j], s1);
            s2 = fmaf(a[j], (float)h2[j], s2);
            s3 = fmaf(a[j], (float)h3[j], s3);
        }
        #pragma unroll
        for (int off = 32; off > 0; off >>= 1) {
            s0 += __shfl_xor(s0, off, 64);
            s1 += __shfl_xor(s1, off, 64);
            s2 += __shfl_xor(s2, off, 64);
            s3 += __shfl_xor(s3, off, 64);
        }
        if (lane == 0) {
            out[k0 & 0x3FFFFu] = 1.0f / (1.0f + expf(-s0));
            out[k1 & 0x3FFFFu] = 1.0f / (1.0f + expf(-s1));
            out[k2 & 0x3FFFFu] = 1.0f / (1.0f + expf(-s2));
            out[k3 & 0x3FFFFu] = 1.0f / (1.0f + expf(-s3));
        }
    }
    for (; i < end; ++i) {
        unsigned k = keys[i];
        half8 h = *(const half8*)(Zh + (size_t)(k >> 18) * DIM + lane * 8);
        float s = a[0] * (float)h[0];
        #pragma unroll
        for (int j = 1; j < 8; ++j)
            s = fmaf(a[j], (float)h[j], s);
        #pragma unroll
        for (int off = 32; off > 0; off >>= 1)
            s += __shfl_xor(s, off, 64);
        if (lane == 0)
            out[k & 0x3FFFFu] = 1.0f / (1.0f + expf(-s));
    }
}

// ---------------------------------------------------------------------------
// Fallback edge scoring (unsorted, fp32)
// ---------------------------------------------------------------------------
__global__ __launch_bounds__(256) void edge_score(const float* __restrict__ ZW,
                                                  const float* __restrict__ Z,
                                                  const int* __restrict__ eidx,
                                                  float* __restrict__ out) {
    const int e    = blockIdx.x * 4 + (threadIdx.x >> 6);
    const int lane = threadIdx.x & 63;

    const int r = eidx[e];
    const int c = eidx[NEDGES + e];

    const float4* pr = (const float4*)(ZW + (size_t)r * DIM);
    const float4* pc = (const float4*)(Z  + (size_t)c * DIM);

    float4 a0 = pr[lane * 2 + 0];
    float4 a1 = pr[lane * 2 + 1];
    float4 b0 = pc[lane * 2 + 0];
    float4 b1 = pc[lane * 2 + 1];

    float s = a0.x * b0.x;
    s = fmaf(a0.y, b0.y, s);
    s = fmaf(a0.z, b0.z, s);
    s = fmaf(a0.w, b0.w, s);
    s = fmaf(a1.x, b1.x, s);
    s = fmaf(a1.y, b1.y, s);
    s = fmaf(a1.z, b1.z, s);
    s = fmaf(a1.w, b1.w, s);

    #pragma unroll
    for (int off = 32; off > 0; off >>= 1)
        s += __shfl_xor(s, off, 64);

    if (lane == 0)
        out[e] = 1.0f / (1.0f + expf(-s));
}

// ---------------------------------------------------------------------------
extern "C" void kernel_launch(void* const* d_in, const int* in_sizes, int n_in,
                              void* d_out, int out_size, void* d_ws, size_t ws_size,
                              hipStream_t stream) {
    const float* Z  = (const float*)d_in[0];
    const float* W  = (const float*)d_in[1];
    const int*   EI = (const int*)d_in[2];
    float* out = (float*)d_out;

    char* p = (char*)d_ws;
    float* ZW = (float*)p;                     p += (size_t)NNODES * DIM * 4;
    _Float16* Zh16 = (_Float16*)p;             p += (size_t)MPAD * DIM * 2;
    unsigned short* Wht = (unsigned short*)p;  p += (size_t)DIM * DIM * 2;
    unsigned short* Wlt = (unsigned short*)p;  p += (size_t)DIM * DIM * 2;
    int* counts = (int*)p;                     p += (size_t)NNODES * 4;
    int* offs   = (int*)p;                     p += (size_t)(NNODES + 1) * 4;
    int* cursor = (int*)p;                     p += (size_t)NNODES * 4;
    unsigned* keys = (unsigned*)p;             p += (size_t)NEDGES * 4;
    const size_t need_full = (size_t)(p - (char*)d_ws);

    if (ws_size >= need_full) {
        split_w<<<64, 256, 0, stream>>>(W, Wht, Wlt, counts);            // + zero counts
        gemm_mfma<<<NMB * 4, 256, 0, stream>>>(Z, Wht, Wlt, ZW, Zh16);   // + emit Zh16
        hist_rows<<<(NEDGES + 255) / 256, 256, 0, stream>>>(EI, counts);
        scan_counts<<<1, 1024, 0, stream>>>(counts, offs, cursor);
        scatter_edges<<<(NEDGES + 255) / 256, 256, 0, stream>>>(EI, cursor, keys);
        edge_score_h<<<NNODES, 64, 0, stream>>>(ZW, Zh16, keys, offs, out);
    } else {
        dim3 g1((NNODES + GTM - 1) / GTM, DIM / GTN);
        gemm_zw<<<g1, 256, 0, stream>>>(Z, W, ZW);
        edge_score<<<NEDGES / 4, 256, 0, stream>>>(ZW, Z, EI, out);
    }
}

// Round 8
// 168.044 us; speedup vs baseline: 1.0138x; 1.0138x over previous
//
#include <hip/hip_runtime.h>
#include <math.h>

#define DIM     512
#define NNODES  10000
#define NEDGES  200000
#define MPAD    10048   // 157 * 64
#define NMB     157     // m-groups of 64

using short8  = __attribute__((ext_vector_type(8))) short;
using floatx4 = __attribute__((ext_vector_type(4))) float;
using half8   = __attribute__((ext_vector_type(8))) _Float16;

__device__ inline unsigned short f32_to_bf16_rn(float x) {
    unsigned u = __float_as_uint(x);
    unsigned r = (u + 0x7FFF + ((u >> 16) & 1)) >> 16;
    return (unsigned short)r;
}
__device__ inline float bf16_to_f32(unsigned short h) {
    return __uint_as_float(((unsigned)h) << 16);
}

// ---------------------------------------------------------------------------
// split_z: Z fp32 [10000][512] -> Zhi, Zlo (bf16 [MPAD][512]) + Zh16 (fp16).
// Pad rows (>=NNODES) are zeroed. 4 elems/thread, grid 5024.
// ---------------------------------------------------------------------------
__global__ __launch_bounds__(256) void split_z(const float* __restrict__ Z,
                                               unsigned short* __restrict__ Zhi,
                                               unsigned short* __restrict__ Zlo,
                                               unsigned short* __restrict__ Zh16) {
    const int base = (blockIdx.x * 256 + threadIdx.x) * 4;
    const int m = base >> 9;
    float4 v = make_float4(0.f, 0.f, 0.f, 0.f);
    if (m < NNODES) v = *(const float4*)(Z + base);
    float x[4] = {v.x, v.y, v.z, v.w};
    ushort4 hi, lo, h16;
    unsigned short* hp = (unsigned short*)&hi;
    unsigned short* lp = (unsigned short*)&lo;
    _Float16* fp = (_Float16*)&h16;
    #pragma unroll
    for (int i = 0; i < 4; ++i) {
        unsigned short h = f32_to_bf16_rn(x[i]);
        hp[i] = h;
        lp[i] = f32_to_bf16_rn(x[i] - bf16_to_f32(h));
        fp[i] = (_Float16)x[i];
    }
    *(ushort4*)(Zhi + base)  = hi;
    *(ushort4*)(Zlo + base)  = lo;
    *(ushort4*)(Zh16 + base) = h16;
}

// ---------------------------------------------------------------------------
// split_w: W (fp32 [k][n]) -> Wht, Wlt (bf16 [n][k]) via LDS tile transpose.
// Grid 64 blocks. Also zeroes counts.
// ---------------------------------------------------------------------------
__global__ __launch_bounds__(256) void split_w(const float* __restrict__ W,
                                               unsigned short* __restrict__ Wht,
                                               unsigned short* __restrict__ Wlt,
                                               int* __restrict__ counts) {
    __shared__ float tile[64][65];
    const int tg = blockIdx.x * 256 + threadIdx.x;
    if (tg < NNODES) counts[tg] = 0;

    const int kb = (blockIdx.x >> 3) * 64;
    const int nb = (blockIdx.x & 7) * 64;
    const int kk = threadIdx.x >> 2;
    const int ch = threadIdx.x & 3;

    const float* src = W + (size_t)(kb + kk) * DIM + nb + ch * 16;
    #pragma unroll
    for (int q = 0; q < 4; ++q) {
        float4 v = *(const float4*)(src + q * 4);
        tile[kk][ch * 16 + q * 4 + 0] = v.x;
        tile[kk][ch * 16 + q * 4 + 1] = v.y;
        tile[kk][ch * 16 + q * 4 + 2] = v.z;
        tile[kk][ch * 16 + q * 4 + 3] = v.w;
    }
    __syncthreads();

    const int nn = kk;
    unsigned short hi[16], lo[16];
    #pragma unroll
    for (int i = 0; i < 16; ++i) {
        float x = tile[ch * 16 + i][nn];
        unsigned short h = f32_to_bf16_rn(x);
        hi[i] = h;
        lo[i] = f32_to_bf16_rn(x - bf16_to_f32(h));
    }
    unsigned short* dh = Wht + (size_t)(nb + nn) * DIM + kb + ch * 16;
    unsigned short* dl = Wlt + (size_t)(nb + nn) * DIM + kb + ch * 16;
    *(short8*)(dh)     = *(short8*)&hi[0];
    *(short8*)(dh + 8) = *(short8*)&hi[8];
    *(short8*)(dl)     = *(short8*)&lo[0];
    *(short8*)(dl + 8) = *(short8*)&lo[8];
}

// ---------------------------------------------------------------------------
// GEMM v6: 64m x 128n block, BK=32, 16 steps, grid 628.
// ALL operands via global_load_lds from bf16 tables (L2/L3-resident),
// double-buffered (48 KB) -> ONE barrier per step:
//     stage(buf^1, next) ; compute(buf) ; __syncthreads()
// The sync's vmcnt(0) drain waits on loads that had the whole compute
// phase to fly. No ds_write, no long-latency HBM load between barriers.
// ---------------------------------------------------------------------------
__global__ __launch_bounds__(256) void gemm_mfma(const unsigned short* __restrict__ Zhi,
                                                 const unsigned short* __restrict__ Zlo,
                                                 const unsigned short* __restrict__ Wht,
                                                 const unsigned short* __restrict__ Wlt,
                                                 float* __restrict__ ZW) {
    __shared__ unsigned short Abuf[2][2][64 * 32];    // [buf][hi/lo][row*32+k]
    __shared__ unsigned short Bbuf[2][2][128 * 32];

    const int t     = threadIdx.x;
    const int bid   = blockIdx.x;
    const int n_idx = bid & 3;
    const int m0    = (bid >> 2) * 64;
    const int n0    = n_idx * 128;

    const int l  = t & 63;
    const int w  = t >> 6;
    const int wn = w * 32;
    const int lm = l & 15;
    const int lq = l >> 4;
    const unsigned wbase = (unsigned)(t & 192);

    floatx4 acc[4][2] = {};

    const int arow = t >> 2;       // A slot row (0..63)
    const int ach  = t & 3;        // 16B chunk within 64B row

    auto stage = [&](int buf, int k0) {
        // A: 256 slots of 16B per table (1 glds/thread/table)
        {
            const unsigned short* sH = Zhi + (size_t)(m0 + arow) * DIM + k0 + ach * 8;
            const unsigned short* sL = Zlo + (size_t)(m0 + arow) * DIM + k0 + ach * 8;
            __builtin_amdgcn_global_load_lds(
                (const __attribute__((address_space(1))) void*)sH,
                (__attribute__((address_space(3))) void*)&Abuf[buf][0][wbase * 8], 16, 0, 0);
            __builtin_amdgcn_global_load_lds(
                (const __attribute__((address_space(1))) void*)sL,
                (__attribute__((address_space(3))) void*)&Abuf[buf][1][wbase * 8], 16, 0, 0);
        }
        // B: 512 slots of 16B per table (2 glds/thread/table)
        #pragma unroll
        for (int p = 0; p < 2; ++p) {
            const int s   = p * 256 + t;
            const int row = s >> 2;
            const int ch  = s & 3;
            const unsigned short* sH = Wht + (size_t)(n0 + row) * DIM + k0 + ch * 8;
            const unsigned short* sL = Wlt + (size_t)(n0 + row) * DIM + k0 + ch * 8;
            __builtin_amdgcn_global_load_lds(
                (const __attribute__((address_space(1))) void*)sH,
                (__attribute__((address_space(3))) void*)&Bbuf[buf][0][(p * 256 + wbase) * 8], 16, 0, 0);
            __builtin_amdgcn_global_load_lds(
                (const __attribute__((address_space(1))) void*)sL,
                (__attribute__((address_space(3))) void*)&Bbuf[buf][1][(p * 256 + wbase) * 8], 16, 0, 0);
        }
    };

    stage(0, 0);
    __syncthreads();

    for (int s = 0; s < 16; ++s) {
        const int buf = s & 1;
        if (s < 15) stage(buf ^ 1, (s + 1) * 32);   // flies across the MFMA phase

        short8 aH[4], aL[4], bH[2], bL[2];
        #pragma unroll
        for (int i = 0; i < 4; ++i) {
            aH[i] = *(const short8*)&Abuf[buf][0][(16 * i + lm) * 32 + lq * 8];
            aL[i] = *(const short8*)&Abuf[buf][1][(16 * i + lm) * 32 + lq * 8];
        }
        #pragma unroll
        for (int j = 0; j < 2; ++j) {
            bH[j] = *(const short8*)&Bbuf[buf][0][(wn + 16 * j + lm) * 32 + lq * 8];
            bL[j] = *(const short8*)&Bbuf[buf][1][(wn + 16 * j + lm) * 32 + lq * 8];
        }
        #pragma unroll
        for (int i = 0; i < 4; ++i)
            #pragma unroll
            for (int j = 0; j < 2; ++j)
                acc[i][j] = __builtin_amdgcn_mfma_f32_16x16x32_bf16(aH[i], bH[j], acc[i][j], 0, 0, 0);
        #pragma unroll
        for (int i = 0; i < 4; ++i)
            #pragma unroll
            for (int j = 0; j < 2; ++j)
                acc[i][j] = __builtin_amdgcn_mfma_f32_16x16x32_bf16(aH[i], bL[j], acc[i][j], 0, 0, 0);
        #pragma unroll
        for (int i = 0; i < 4; ++i)
            #pragma unroll
            for (int j = 0; j < 2; ++j)
                acc[i][j] = __builtin_amdgcn_mfma_f32_16x16x32_bf16(aL[i], bH[j], acc[i][j], 0, 0, 0);

        __syncthreads();   // single barrier: drains prefetch (overlapped) + WAR-safe (dbuf)
    }

    #pragma unroll
    for (int i = 0; i < 4; ++i)
        #pragma unroll
        for (int j = 0; j < 2; ++j)
            #pragma unroll
            for (int r = 0; r < 4; ++r) {
                const int gm = m0 + 16 * i + lq * 4 + r;
                const int gn = n0 + wn + 16 * j + lm;
                if (gm < NNODES)
                    ZW[(size_t)gm * DIM + gn] = acc[i][j][r];
            }
}

// ---------------------------------------------------------------------------
// fp32 GEMM fallback (ws too small)
// ---------------------------------------------------------------------------
#define GTM 128
#define GTN 64
#define GTK 16
#define LDA 132
#define LDB 68

__global__ __launch_bounds__(256) void gemm_zw(const float* __restrict__ A,
                                               const float* __restrict__ B,
                                               float* __restrict__ C) {
    __shared__ float As[GTK * LDA];
    __shared__ float Bs[GTK * LDB];

    const int t  = threadIdx.x;
    const int m0 = blockIdx.x * GTM;
    const int n0 = blockIdx.y * GTN;
    const int tx = t & 15;
    const int ty = t >> 4;

    float acc[8][4] = {};

    for (int k0 = 0; k0 < DIM; k0 += GTK) {
        #pragma unroll
        for (int p = 0; p < 2; ++p) {
            int f  = t + p * 256;
            int mm = f >> 2;
            int kq = f & 3;
            int m  = m0 + mm;
            float4 v = make_float4(0.f, 0.f, 0.f, 0.f);
            if (m < NNODES)
                v = *(const float4*)(A + (size_t)m * DIM + k0 + kq * 4);
            As[(kq * 4 + 0) * LDA + mm] = v.x;
            As[(kq * 4 + 1) * LDA + mm] = v.y;
            As[(kq * 4 + 2) * LDA + mm] = v.z;
            As[(kq * 4 + 3) * LDA + mm] = v.w;
        }
        {
            int kb = t >> 4, n4 = t & 15;
            *(float4*)&Bs[kb * LDB + n4 * 4] =
                *(const float4*)(B + (size_t)(k0 + kb) * DIM + n0 + n4 * 4);
        }
        __syncthreads();

        #pragma unroll
        for (int kk = 0; kk < GTK; ++kk) {
            float4 a0 = *(const float4*)&As[kk * LDA + ty * 8];
            float4 a1 = *(const float4*)&As[kk * LDA + ty * 8 + 4];
            float4 b  = *(const float4*)&Bs[kk * LDB + tx * 4];
            float av[8] = {a0.x, a0.y, a0.z, a0.w, a1.x, a1.y, a1.z, a1.w};
            float bv[4] = {b.x, b.y, b.z, b.w};
            #pragma unroll
            for (int i = 0; i < 8; ++i)
                #pragma unroll
                for (int j = 0; j < 4; ++j)
                    acc[i][j] = fmaf(av[i], bv[j], acc[i][j]);
        }
        __syncthreads();
    }

    #pragma unroll
    for (int i = 0; i < 8; ++i) {
        int m = m0 + ty * 8 + i;
        if (m < NNODES)
            *(float4*)(C + (size_t)m * DIM + n0 + tx * 4) =
                make_float4(acc[i][0], acc[i][1], acc[i][2], acc[i][3]);
    }
}

// ---------------------------------------------------------------------------
// Counting sort of edges by row
// ---------------------------------------------------------------------------
__global__ void hist_rows(const int* __restrict__ eidx, int* __restrict__ counts) {
    int e = blockIdx.x * blockDim.x + threadIdx.x;
    if (e < NEDGES) atomicAdd(&counts[eidx[e]], 1);
}

__global__ __launch_bounds__(1024) void scan_counts(const int* __restrict__ counts,
                                                    int* __restrict__ offs,
                                                    int* __restrict__ cursor) {
    __shared__ int wsum[16];
    __shared__ int woff[17];
    const int t    = threadIdx.x;
    const int lane = t & 63;
    const int wv   = t >> 6;

    int local[10];
    int s = 0;
    if (t < 1000) {
        #pragma unroll
        for (int j = 0; j < 10; ++j) {
            local[j] = counts[t * 10 + j];
            s += local[j];
        }
    }
    int v = s;
    #pragma unroll
    for (int off = 1; off < 64; off <<= 1) {
        int u = __shfl_up(v, off, 64);
        if (lane >= off) v += u;
    }
    if (lane == 63) wsum[wv] = v;
    __syncthreads();
    if (t == 0) {
        int r = 0;
        #pragma unroll
        for (int i = 0; i < 16; ++i) { woff[i] = r; r += wsum[i]; }
        woff[16] = r;
    }
    __syncthreads();
    if (t < 1000) {
        int run = woff[wv] + (v - s);
        #pragma unroll
        for (int j = 0; j < 10; ++j) {
            offs[t * 10 + j]   = run;
            cursor[t * 10 + j] = run;
            run += local[j];
        }
    }
    if (t == 0) offs[NNODES] = woff[16];
}

__global__ void scatter_edges(const int* __restrict__ eidx,
                              int* __restrict__ cursor,
                              unsigned* __restrict__ keys) {
    int e = blockIdx.x * blockDim.x + threadIdx.x;
    if (e < NEDGES) {
        int r = eidx[e];
        int c = eidx[NEDGES + e];
        int pos = atomicAdd(&cursor[r], 1);
        keys[pos] = ((unsigned)c << 18) | (unsigned)e;
    }
}

// ---------------------------------------------------------------------------
// Edge scoring: one wave per row bucket; ZW row in regs; fp16 col gather.
// ---------------------------------------------------------------------------
__global__ __launch_bounds__(64) void edge_score_h(const float* __restrict__ ZW,
                                                   const _Float16* __restrict__ Zh,
                                                   const unsigned* __restrict__ keys,
                                                   const int* __restrict__ offs,
                                                   float* __restrict__ out) {
    const int r = blockIdx.x;
    const int start = offs[r];
    const int end   = offs[r + 1];
    if (start == end) return;

    const int lane = threadIdx.x;
    const float4 a0 = *(const float4*)(ZW + (size_t)r * DIM + lane * 8);
    const float4 a1 = *(const float4*)(ZW + (size_t)r * DIM + lane * 8 + 4);
    const float a[8] = {a0.x, a0.y, a0.z, a0.w, a1.x, a1.y, a1.z, a1.w};

    int i = start;
    for (; i + 3 < end; i += 4) {
        unsigned k0 = keys[i], k1 = keys[i + 1], k2 = keys[i + 2], k3 = keys[i + 3];
        half8 h0 = *(const half8*)(Zh + (size_t)(k0 >> 18) * DIM + lane * 8);
        half8 h1 = *(const half8*)(Zh + (size_t)(k1 >> 18) * DIM + lane * 8);
        half8 h2 = *(const half8*)(Zh + (size_t)(k2 >> 18) * DIM + lane * 8);
        half8 h3 = *(const half8*)(Zh + (size_t)(k3 >> 18) * DIM + lane * 8);

        float s0 = a[0] * (float)h0[0], s1 = a[0] * (float)h1[0];
        float s2 = a[0] * (float)h2[0], s3 = a[0] * (float)h3[0];
        #pragma unroll
        for (int j = 1; j < 8; ++j) {
            s0 = fmaf(a[j], (float)h0[j], s0);
            s1 = fmaf(a[j], (float)h1[j], s1);
            s2 = fmaf(a[j], (float)h2[j], s2);
            s3 = fmaf(a[j], (float)h3[j], s3);
        }
        #pragma unroll
        for (int off = 32; off > 0; off >>= 1) {
            s0 += __shfl_xor(s0, off, 64);
            s1 += __shfl_xor(s1, off, 64);
            s2 += __shfl_xor(s2, off, 64);
            s3 += __shfl_xor(s3, off, 64);
        }
        if (lane == 0) {
            out[k0 & 0x3FFFFu] = 1.0f / (1.0f + expf(-s0));
            out[k1 & 0x3FFFFu] = 1.0f / (1.0f + expf(-s1));
            out[k2 & 0x3FFFFu] = 1.0f / (1.0f + expf(-s2));
            out[k3 & 0x3FFFFu] = 1.0f / (1.0f + expf(-s3));
        }
    }
    for (; i < end; ++i) {
        unsigned k = keys[i];
        half8 h = *(const half8*)(Zh + (size_t)(k >> 18) * DIM + lane * 8);
        float s = a[0] * (float)h[0];
        #pragma unroll
        for (int j = 1; j < 8; ++j)
            s = fmaf(a[j], (float)h[j], s);
        #pragma unroll
        for (int off = 32; off > 0; off >>= 1)
            s += __shfl_xor(s, off, 64);
        if (lane == 0)
            out[k & 0x3FFFFu] = 1.0f / (1.0f + expf(-s));
    }
}

// ---------------------------------------------------------------------------
// Fallback edge scoring (unsorted, fp32)
// ---------------------------------------------------------------------------
__global__ __launch_bounds__(256) void edge_score(const float* __restrict__ ZW,
                                                  const float* __restrict__ Z,
                                                  const int* __restrict__ eidx,
                                                  float* __restrict__ out) {
    const int e    = blockIdx.x * 4 + (threadIdx.x >> 6);
    const int lane = threadIdx.x & 63;

    const int r = eidx[e];
    const int c = eidx[NEDGES + e];

    const float4* pr = (const float4*)(ZW + (size_t)r * DIM);
    const float4* pc = (const float4*)(Z  + (size_t)c * DIM);

    float4 a0 = pr[lane * 2 + 0];
    float4 a1 = pr[lane * 2 + 1];
    float4 b0 = pc[lane * 2 + 0];
    float4 b1 = pc[lane * 2 + 1];

    float s = a0.x * b0.x;
    s = fmaf(a0.y, b0.y, s);
    s = fmaf(a0.z, b0.z, s);
    s = fmaf(a0.w, b0.w, s);
    s = fmaf(a1.x, b1.x, s);
    s = fmaf(a1.y, b1.y, s);
    s = fmaf(a1.z, b1.z, s);
    s = fmaf(a1.w, b1.w, s);

    #pragma unroll
    for (int off = 32; off > 0; off >>= 1)
        s += __shfl_xor(s, off, 64);

    if (lane == 0)
        out[e] = 1.0f / (1.0f + expf(-s));
}

// ---------------------------------------------------------------------------
extern "C" void kernel_launch(void* const* d_in, const int* in_sizes, int n_in,
                              void* d_out, int out_size, void* d_ws, size_t ws_size,
                              hipStream_t stream) {
    const float* Z  = (const float*)d_in[0];
    const float* W  = (const float*)d_in[1];
    const int*   EI = (const int*)d_in[2];
    float* out = (float*)d_out;

    char* p = (char*)d_ws;
    float* ZW = (float*)p;                     p += (size_t)NNODES * DIM * 4;
    unsigned short* Zhi  = (unsigned short*)p; p += (size_t)MPAD * DIM * 2;
    unsigned short* Zlo  = (unsigned short*)p; p += (size_t)MPAD * DIM * 2;
    unsigned short* Zh16 = (unsigned short*)p; p += (size_t)MPAD * DIM * 2;
    unsigned short* Wht  = (unsigned short*)p; p += (size_t)DIM * DIM * 2;
    unsigned short* Wlt  = (unsigned short*)p; p += (size_t)DIM * DIM * 2;
    int* counts = (int*)p;                     p += (size_t)NNODES * 4;
    int* offs   = (int*)p;                     p += (size_t)(NNODES + 1) * 4;
    int* cursor = (int*)p;                     p += (size_t)NNODES * 4;
    unsigned* keys = (unsigned*)p;             p += (size_t)NEDGES * 4;
    const size_t need_full = (size_t)(p - (char*)d_ws);

    if (ws_size >= need_full) {
        split_z<<<MPAD * DIM / 4 / 256, 256, 0, stream>>>(Z, Zhi, Zlo, Zh16);
        split_w<<<64, 256, 0, stream>>>(W, Wht, Wlt, counts);            // + zero counts
        gemm_mfma<<<NMB * 4, 256, 0, stream>>>(Zhi, Zlo, Wht, Wlt, ZW);
        hist_rows<<<(NEDGES + 255) / 256, 256, 0, stream>>>(EI, counts);
        scan_counts<<<1, 1024, 0, stream>>>(counts, offs, cursor);
        scatter_edges<<<(NEDGES + 255) / 256, 256, 0, stream>>>(EI, cursor, keys);
        edge_score_h<<<NNODES, 64, 0, stream>>>(ZW, (const _Float16*)Zh16, keys, offs, out);
    } else {
        dim3 g1((NNODES + GTM - 1) / GTM, DIM / GTN);
        gemm_zw<<<g1, 256, 0, stream>>>(Z, W, ZW);
        edge_score<<<NEDGES / 4, 256, 0, stream>>>(ZW, Z, EI, out);
    }
}

// Round 9
// 147.833 us; speedup vs baseline: 1.1523x; 1.1367x over previous
//
#include <hip/hip_runtime.h>
#include <math.h>

#define DIM     512
#define NNODES  10000
#define NEDGES  200000
#define MPAD    10048   // 157 * 64
#define NMB     157     // m-groups of 64

using short8  = __attribute__((ext_vector_type(8))) short;
using floatx4 = __attribute__((ext_vector_type(4))) float;
using half8   = __attribute__((ext_vector_type(8))) _Float16;

// ---------------------------------------------------------------------------
// prep: fused  (a) Z fp32 -> Zh16 fp16 [MPAD][512] (pad rows zeroed)
//              (b) W fp32 [k][n] -> Wh16t fp16 [n][k] (LDS tile transpose)
//              (c) zero counts
// Grid: 2512 blocks for (a) + 64 blocks for (b). (c) rides on blocks 0..39.
// ---------------------------------------------------------------------------
#define PREP_ZBLK 2512
__global__ __launch_bounds__(256) void prep(const float* __restrict__ Z,
                                            const float* __restrict__ W,
                                            _Float16* __restrict__ Zh16,
                                            _Float16* __restrict__ Wh16t,
                                            int* __restrict__ counts) {
    const int b = blockIdx.x;
    const int t = threadIdx.x;

    if (b < 40) {
        int i = b * 256 + t;
        if (i < NNODES) counts[i] = 0;
    }

    if (b < PREP_ZBLK) {
        // (a) 8 halves per thread
        const int idx8 = (b * 256 + t) * 8;
        const int m = idx8 >> 9;
        float x[8];
        if (m < NNODES) {
            float4 v0 = *(const float4*)(Z + idx8);
            float4 v1 = *(const float4*)(Z + idx8 + 4);
            x[0]=v0.x; x[1]=v0.y; x[2]=v0.z; x[3]=v0.w;
            x[4]=v1.x; x[5]=v1.y; x[6]=v1.z; x[7]=v1.w;
        } else {
            #pragma unroll
            for (int j = 0; j < 8; ++j) x[j] = 0.f;
        }
        half8 h;
        #pragma unroll
        for (int j = 0; j < 8; ++j) h[j] = (_Float16)x[j];
        *(half8*)(Zh16 + idx8) = h;
    } else {
        // (b) W transpose: 64x64 tile per block
        __shared__ float tile[64][65];
        const int wb = b - PREP_ZBLK;      // 0..63
        const int kb = (wb >> 3) * 64;
        const int nb = (wb & 7) * 64;
        const int kk = t >> 2;
        const int ch = t & 3;

        const float* src = W + (size_t)(kb + kk) * DIM + nb + ch * 16;
        #pragma unroll
        for (int q = 0; q < 4; ++q) {
            float4 v = *(const float4*)(src + q * 4);
            tile[kk][ch * 16 + q * 4 + 0] = v.x;
            tile[kk][ch * 16 + q * 4 + 1] = v.y;
            tile[kk][ch * 16 + q * 4 + 2] = v.z;
            tile[kk][ch * 16 + q * 4 + 3] = v.w;
        }
        __syncthreads();

        const int nn = kk;
        half8 h0, h1;
        #pragma unroll
        for (int i = 0; i < 8; ++i) h0[i] = (_Float16)tile[ch * 16 + i][nn];
        #pragma unroll
        for (int i = 0; i < 8; ++i) h1[i] = (_Float16)tile[ch * 16 + 8 + i][nn];
        _Float16* d = Wh16t + (size_t)(nb + nn) * DIM + kb + ch * 16;
        *(half8*)(d)     = h0;
        *(half8*)(d + 8) = h1;
    }
}

// ---------------------------------------------------------------------------
// GEMM v7: single-pass fp16 MFMA.  64m x 128n block, BK=32, 16 steps,
// grid 628 (157x4).  A/B staged via global_load_lds into double-buffered
// LDS (24 KB -> ~6 blocks/CU), ONE barrier per step:
//     stage(buf^1, next) ; compute(buf) ; __syncthreads()
// Output ZW written as fp16 (edge row reads halve).
// ---------------------------------------------------------------------------
__global__ __launch_bounds__(256) void gemm_f16(const _Float16* __restrict__ Zh16,
                                                const _Float16* __restrict__ Wh16t,
                                                _Float16* __restrict__ ZWh) {
    __shared__ _Float16 Abuf[2][64 * 32];
    __shared__ _Float16 Bbuf[2][128 * 32];

    const int t     = threadIdx.x;
    const int bid   = blockIdx.x;
    const int n_idx = bid & 3;
    const int m0    = (bid >> 2) * 64;
    const int n0    = n_idx * 128;

    const int l  = t & 63;
    const int w  = t >> 6;
    const int wn = w * 32;
    const int lm = l & 15;
    const int lq = l >> 4;
    const unsigned wbase = (unsigned)(t & 192);

    floatx4 acc[4][2] = {};

    const int arow = t >> 2;   // 0..63
    const int ach  = t & 3;

    auto stage = [&](int buf, int k0) {
        // A: 256 slots of 16B (1 glds/thread)
        {
            const _Float16* s = Zh16 + (size_t)(m0 + arow) * DIM + k0 + ach * 8;
            __builtin_amdgcn_global_load_lds(
                (const __attribute__((address_space(1))) void*)s,
                (__attribute__((address_space(3))) void*)&Abuf[buf][wbase * 8], 16, 0, 0);
        }
        // B: 512 slots of 16B (2 glds/thread)
        #pragma unroll
        for (int p = 0; p < 2; ++p) {
            const int sidx = p * 256 + t;
            const int row  = sidx >> 2;
            const int ch   = sidx & 3;
            const _Float16* s = Wh16t + (size_t)(n0 + row) * DIM + k0 + ch * 8;
            __builtin_amdgcn_global_load_lds(
                (const __attribute__((address_space(1))) void*)s,
                (__attribute__((address_space(3))) void*)&Bbuf[buf][(p * 256 + wbase) * 8], 16, 0, 0);
        }
    };

    stage(0, 0);
    __syncthreads();

    for (int s = 0; s < 16; ++s) {
        const int buf = s & 1;
        if (s < 15) stage(buf ^ 1, (s + 1) * 32);   // flies across MFMA phase

        half8 aF[4], bF[2];
        #pragma unroll
        for (int i = 0; i < 4; ++i)
            aF[i] = *(const half8*)&Abuf[buf][(16 * i + lm) * 32 + lq * 8];
        #pragma unroll
        for (int j = 0; j < 2; ++j)
            bF[j] = *(const half8*)&Bbuf[buf][(wn + 16 * j + lm) * 32 + lq * 8];

        #pragma unroll
        for (int i = 0; i < 4; ++i)
            #pragma unroll
            for (int j = 0; j < 2; ++j)
                acc[i][j] = __builtin_amdgcn_mfma_f32_16x16x32_f16(aF[i], bF[j], acc[i][j], 0, 0, 0);

        __syncthreads();   // drains prefetch (had whole MFMA phase) + WAR-safe (dbuf)
    }

    #pragma unroll
    for (int i = 0; i < 4; ++i)
        #pragma unroll
        for (int j = 0; j < 2; ++j)
            #pragma unroll
            for (int r = 0; r < 4; ++r) {
                const int gm = m0 + 16 * i + lq * 4 + r;
                const int gn = n0 + wn + 16 * j + lm;
                if (gm < NNODES)
                    ZWh[(size_t)gm * DIM + gn] = (_Float16)acc[i][j][r];
            }
}

// ---------------------------------------------------------------------------
// Counting sort of edges by row
// ---------------------------------------------------------------------------
__global__ void hist_rows(const int* __restrict__ eidx, int* __restrict__ counts) {
    int e = blockIdx.x * blockDim.x + threadIdx.x;
    if (e < NEDGES) atomicAdd(&counts[eidx[e]], 1);
}

__global__ __launch_bounds__(1024) void scan_counts(const int* __restrict__ counts,
                                                    int* __restrict__ offs,
                                                    int* __restrict__ cursor) {
    __shared__ int wsum[16];
    __shared__ int woff[17];
    const int t    = threadIdx.x;
    const int lane = t & 63;
    const int wv   = t >> 6;

    int local[10];
    int s = 0;
    if (t < 1000) {
        #pragma unroll
        for (int j = 0; j < 10; ++j) {
            local[j] = counts[t * 10 + j];
            s += local[j];
        }
    }
    int v = s;
    #pragma unroll
    for (int off = 1; off < 64; off <<= 1) {
        int u = __shfl_up(v, off, 64);
        if (lane >= off) v += u;
    }
    if (lane == 63) wsum[wv] = v;
    __syncthreads();
    if (t == 0) {
        int r = 0;
        #pragma unroll
        for (int i = 0; i < 16; ++i) { woff[i] = r; r += wsum[i]; }
        woff[16] = r;
    }
    __syncthreads();
    if (t < 1000) {
        int run = woff[wv] + (v - s);
        #pragma unroll
        for (int j = 0; j < 10; ++j) {
            offs[t * 10 + j]   = run;
            cursor[t * 10 + j] = run;
            run += local[j];
        }
    }
    if (t == 0) offs[NNODES] = woff[16];
}

__global__ void scatter_edges(const int* __restrict__ eidx,
                              int* __restrict__ cursor,
                              unsigned* __restrict__ keys) {
    int e = blockIdx.x * blockDim.x + threadIdx.x;
    if (e < NEDGES) {
        int r = eidx[e];
        int c = eidx[NEDGES + e];
        int pos = atomicAdd(&cursor[r], 1);
        keys[pos] = ((unsigned)c << 18) | (unsigned)e;
    }
}

// ---------------------------------------------------------------------------
// Edge scoring: one wave per row bucket; ZW row (fp16, one b128) in regs;
// fp16 col gather; 4-edge unroll.
// ---------------------------------------------------------------------------
__global__ __launch_bounds__(64) void edge_score_h(const _Float16* __restrict__ ZWh,
                                                   const _Float16* __restrict__ Zh,
                                                   const unsigned* __restrict__ keys,
                                                   const int* __restrict__ offs,
                                                   float* __restrict__ out) {
    const int r = blockIdx.x;
    const int start = offs[r];
    const int end   = offs[r + 1];
    if (start == end) return;

    const int lane = threadIdx.x;
    half8 hr = *(const half8*)(ZWh + (size_t)r * DIM + lane * 8);
    float a[8];
    #pragma unroll
    for (int j = 0; j < 8; ++j) a[j] = (float)hr[j];

    int i = start;
    for (; i + 3 < end; i += 4) {
        unsigned k0 = keys[i], k1 = keys[i + 1], k2 = keys[i + 2], k3 = keys[i + 3];
        half8 h0 = *(const half8*)(Zh + (size_t)(k0 >> 18) * DIM + lane * 8);
        half8 h1 = *(const half8*)(Zh + (size_t)(k1 >> 18) * DIM + lane * 8);
        half8 h2 = *(const half8*)(Zh + (size_t)(k2 >> 18) * DIM + lane * 8);
        half8 h3 = *(const half8*)(Zh + (size_t)(k3 >> 18) * DIM + lane * 8);

        float s0 = a[0] * (float)h0[0], s1 = a[0] * (float)h1[0];
        float s2 = a[0] * (float)h2[0], s3 = a[0] * (float)h3[0];
        #pragma unroll
        for (int j = 1; j < 8; ++j) {
            s0 = fmaf(a[j], (float)h0[j], s0);
            s1 = fmaf(a[j], (float)h1[j], s1);
            s2 = fmaf(a[j], (float)h2[j], s2);
            s3 = fmaf(a[j], (float)h3[j], s3);
        }
        #pragma unroll
        for (int off = 32; off > 0; off >>= 1) {
            s0 += __shfl_xor(s0, off, 64);
            s1 += __shfl_xor(s1, off, 64);
            s2 += __shfl_xor(s2, off, 64);
            s3 += __shfl_xor(s3, off, 64);
        }
        if (lane == 0) {
            out[k0 & 0x3FFFFu] = 1.0f / (1.0f + expf(-s0));
            out[k1 & 0x3FFFFu] = 1.0f / (1.0f + expf(-s1));
            out[k2 & 0x3FFFFu] = 1.0f / (1.0f + expf(-s2));
            out[k3 & 0x3FFFFu] = 1.0f / (1.0f + expf(-s3));
        }
    }
    for (; i < end; ++i) {
        unsigned k = keys[i];
        half8 h = *(const half8*)(Zh + (size_t)(k >> 18) * DIM + lane * 8);
        float s = a[0] * (float)h[0];
        #pragma unroll
        for (int j = 1; j < 8; ++j)
            s = fmaf(a[j], (float)h[j], s);
        #pragma unroll
        for (int off = 32; off > 0; off >>= 1)
            s += __shfl_xor(s, off, 64);
        if (lane == 0)
            out[k & 0x3FFFFu] = 1.0f / (1.0f + expf(-s));
    }
}

// ---------------------------------------------------------------------------
// fp32 fallback path (ws too small): fp32 GEMM + unsorted fp32 edge scoring
// ---------------------------------------------------------------------------
#define GTM 128
#define GTN 64
#define GTK 16
#define LDA 132
#define LDB 68

__global__ __launch_bounds__(256) void gemm_zw(const float* __restrict__ A,
                                               const float* __restrict__ B,
                                               float* __restrict__ C) {
    __shared__ float As[GTK * LDA];
    __shared__ float Bs[GTK * LDB];

    const int t  = threadIdx.x;
    const int m0 = blockIdx.x * GTM;
    const int n0 = blockIdx.y * GTN;
    const int tx = t & 15;
    const int ty = t >> 4;

    float acc[8][4] = {};

    for (int k0 = 0; k0 < DIM; k0 += GTK) {
        #pragma unroll
        for (int p = 0; p < 2; ++p) {
            int f  = t + p * 256;
            int mm = f >> 2;
            int kq = f & 3;
            int m  = m0 + mm;
            float4 v = make_float4(0.f, 0.f, 0.f, 0.f);
            if (m < NNODES)
                v = *(const float4*)(A + (size_t)m * DIM + k0 + kq * 4);
            As[(kq * 4 + 0) * LDA + mm] = v.x;
            As[(kq * 4 + 1) * LDA + mm] = v.y;
            As[(kq * 4 + 2) * LDA + mm] = v.z;
            As[(kq * 4 + 3) * LDA + mm] = v.w;
        }
        {
            int kb = t >> 4, n4 = t & 15;
            *(float4*)&Bs[kb * LDB + n4 * 4] =
                *(const float4*)(B + (size_t)(k0 + kb) * DIM + n0 + n4 * 4);
        }
        __syncthreads();

        #pragma unroll
        for (int kk = 0; kk < GTK; ++kk) {
            float4 a0 = *(const float4*)&As[kk * LDA + ty * 8];
            float4 a1 = *(const float4*)&As[kk * LDA + ty * 8 + 4];
            float4 b  = *(const float4*)&Bs[kk * LDB + tx * 4];
            float av[8] = {a0.x, a0.y, a0.z, a0.w, a1.x, a1.y, a1.z, a1.w};
            float bv[4] = {b.x, b.y, b.z, b.w};
            #pragma unroll
            for (int i = 0; i < 8; ++i)
                #pragma unroll
                for (int j = 0; j < 4; ++j)
                    acc[i][j] = fmaf(av[i], bv[j], acc[i][j]);
        }
        __syncthreads();
    }

    #pragma unroll
    for (int i = 0; i < 8; ++i) {
        int m = m0 + ty * 8 + i;
        if (m < NNODES)
            *(float4*)(C + (size_t)m * DIM + n0 + tx * 4) =
                make_float4(acc[i][0], acc[i][1], acc[i][2], acc[i][3]);
    }
}

__global__ __launch_bounds__(256) void edge_score(const float* __restrict__ ZW,
                                                  const float* __restrict__ Z,
                                                  const int* __restrict__ eidx,
                                                  float* __restrict__ out) {
    const int e    = blockIdx.x * 4 + (threadIdx.x >> 6);
    const int lane = threadIdx.x & 63;

    const int r = eidx[e];
    const int c = eidx[NEDGES + e];

    const float4* pr = (const float4*)(ZW + (size_t)r * DIM);
    const float4* pc = (const float4*)(Z  + (size_t)c * DIM);

    float4 a0 = pr[lane * 2 + 0];
    float4 a1 = pr[lane * 2 + 1];
    float4 b0 = pc[lane * 2 + 0];
    float4 b1 = pc[lane * 2 + 1];

    float s = a0.x * b0.x;
    s = fmaf(a0.y, b0.y, s);
    s = fmaf(a0.z, b0.z, s);
    s = fmaf(a0.w, b0.w, s);
    s = fmaf(a1.x, b1.x, s);
    s = fmaf(a1.y, b1.y, s);
    s = fmaf(a1.z, b1.z, s);
    s = fmaf(a1.w, b1.w, s);

    #pragma unroll
    for (int off = 32; off > 0; off >>= 1)
        s += __shfl_xor(s, off, 64);

    if (lane == 0)
        out[e] = 1.0f / (1.0f + expf(-s));
}

// ---------------------------------------------------------------------------
extern "C" void kernel_launch(void* const* d_in, const int* in_sizes, int n_in,
                              void* d_out, int out_size, void* d_ws, size_t ws_size,
                              hipStream_t stream) {
    const float* Z  = (const float*)d_in[0];
    const float* W  = (const float*)d_in[1];
    const int*   EI = (const int*)d_in[2];
    float* out = (float*)d_out;

    char* p = (char*)d_ws;
    _Float16* ZWh   = (_Float16*)p;  p += (size_t)MPAD * DIM * 2;    // 10.3 MB
    _Float16* Zh16  = (_Float16*)p;  p += (size_t)MPAD * DIM * 2;    // 10.3 MB
    _Float16* Wh16t = (_Float16*)p;  p += (size_t)DIM * DIM * 2;     // 0.5 MB
    int* counts = (int*)p;           p += (size_t)NNODES * 4;
    int* offs   = (int*)p;           p += (size_t)(NNODES + 1) * 4;
    int* cursor = (int*)p;           p += (size_t)NNODES * 4;
    unsigned* keys = (unsigned*)p;   p += (size_t)NEDGES * 4;
    const size_t need_full = (size_t)(p - (char*)d_ws);

    if (ws_size >= need_full) {
        prep<<<PREP_ZBLK + 64, 256, 0, stream>>>(Z, W, Zh16, Wh16t, counts);
        gemm_f16<<<NMB * 4, 256, 0, stream>>>(Zh16, Wh16t, ZWh);
        hist_rows<<<(NEDGES + 255) / 256, 256, 0, stream>>>(EI, counts);
        scan_counts<<<1, 1024, 0, stream>>>(counts, offs, cursor);
        scatter_edges<<<(NEDGES + 255) / 256, 256, 0, stream>>>(EI, cursor, keys);
        edge_score_h<<<NNODES, 64, 0, stream>>>(ZWh, Zh16, keys, offs, out);
    } else {
        // fp32 fallback: reuse ws base as fp32 ZW (20.5 MB needed)
        float* ZW = (float*)d_ws;
        dim3 g1((NNODES + GTM - 1) / GTM, DIM / GTN);
        gemm_zw<<<g1, 256, 0, stream>>>(Z, W, ZW);
        edge_score<<<NEDGES / 4, 256, 0, stream>>>(ZW, Z, EI, out);
    }
}

// Round 10
// 145.764 us; speedup vs baseline: 1.1687x; 1.0142x over previous
//
#include <hip/hip_runtime.h>
#include <math.h>

#define DIM     512
#define NNODES  10000
#define NEDGES  200000
#define MPAD    10048   // 157 * 64
#define NMB     157     // m-groups of 64

using short8  = __attribute__((ext_vector_type(8))) short;
using floatx4 = __attribute__((ext_vector_type(4))) float;
using half8   = __attribute__((ext_vector_type(8))) _Float16;
using half2v  = __attribute__((ext_vector_type(2))) _Float16;

__device__ inline float dot2acc(half2v a, half2v b, float c) {
#if __has_builtin(__builtin_amdgcn_fdot2)
    return __builtin_amdgcn_fdot2(a, b, c, false);
#else
    return fmaf((float)a[0], (float)b[0], fmaf((float)a[1], (float)b[1], c));
#endif
}

// ---------------------------------------------------------------------------
// prep: fused  (a) Z fp32 -> Zh16 fp16 [MPAD][512] (pad rows zeroed)
//              (b) W fp32 [k][n] -> Wh16t fp16 [n][k] (LDS tile transpose)
//              (c) zero counts
// ---------------------------------------------------------------------------
#define PREP_ZBLK 2512
__global__ __launch_bounds__(256) void prep(const float* __restrict__ Z,
                                            const float* __restrict__ W,
                                            _Float16* __restrict__ Zh16,
                                            _Float16* __restrict__ Wh16t,
                                            int* __restrict__ counts) {
    const int b = blockIdx.x;
    const int t = threadIdx.x;

    if (b < 40) {
        int i = b * 256 + t;
        if (i < NNODES) counts[i] = 0;
    }

    if (b < PREP_ZBLK) {
        const int idx8 = (b * 256 + t) * 8;
        const int m = idx8 >> 9;
        float x[8];
        if (m < NNODES) {
            float4 v0 = *(const float4*)(Z + idx8);
            float4 v1 = *(const float4*)(Z + idx8 + 4);
            x[0]=v0.x; x[1]=v0.y; x[2]=v0.z; x[3]=v0.w;
            x[4]=v1.x; x[5]=v1.y; x[6]=v1.z; x[7]=v1.w;
        } else {
            #pragma unroll
            for (int j = 0; j < 8; ++j) x[j] = 0.f;
        }
        half8 h;
        #pragma unroll
        for (int j = 0; j < 8; ++j) h[j] = (_Float16)x[j];
        *(half8*)(Zh16 + idx8) = h;
    } else {
        __shared__ float tile[64][65];
        const int wb = b - PREP_ZBLK;      // 0..63
        const int kb = (wb >> 3) * 64;
        const int nb = (wb & 7) * 64;
        const int kk = t >> 2;
        const int ch = t & 3;

        const float* src = W + (size_t)(kb + kk) * DIM + nb + ch * 16;
        #pragma unroll
        for (int q = 0; q < 4; ++q) {
            float4 v = *(const float4*)(src + q * 4);
            tile[kk][ch * 16 + q * 4 + 0] = v.x;
            tile[kk][ch * 16 + q * 4 + 1] = v.y;
            tile[kk][ch * 16 + q * 4 + 2] = v.z;
            tile[kk][ch * 16 + q * 4 + 3] = v.w;
        }
        __syncthreads();

        const int nn = kk;
        half8 h0, h1;
        #pragma unroll
        for (int i = 0; i < 8; ++i) h0[i] = (_Float16)tile[ch * 16 + i][nn];
        #pragma unroll
        for (int i = 0; i < 8; ++i) h1[i] = (_Float16)tile[ch * 16 + 8 + i][nn];
        _Float16* d = Wh16t + (size_t)(nb + nn) * DIM + kb + ch * 16;
        *(half8*)(d)     = h0;
        *(half8*)(d + 8) = h1;
    }
}

// ---------------------------------------------------------------------------
// GEMM: single-pass fp16 MFMA.  64m x 128n block, BK=32, 16 steps, grid 628.
// A/B via global_load_lds into double-buffered LDS, ONE barrier per step.
// ---------------------------------------------------------------------------
__global__ __launch_bounds__(256) void gemm_f16(const _Float16* __restrict__ Zh16,
                                                const _Float16* __restrict__ Wh16t,
                                                _Float16* __restrict__ ZWh) {
    __shared__ _Float16 Abuf[2][64 * 32];
    __shared__ _Float16 Bbuf[2][128 * 32];

    const int t     = threadIdx.x;
    const int bid   = blockIdx.x;
    const int n_idx = bid & 3;
    const int m0    = (bid >> 2) * 64;
    const int n0    = n_idx * 128;

    const int l  = t & 63;
    const int w  = t >> 6;
    const int wn = w * 32;
    const int lm = l & 15;
    const int lq = l >> 4;
    const unsigned wbase = (unsigned)(t & 192);

    floatx4 acc[4][2] = {};

    const int arow = t >> 2;
    const int ach  = t & 3;

    auto stage = [&](int buf, int k0) {
        {
            const _Float16* s = Zh16 + (size_t)(m0 + arow) * DIM + k0 + ach * 8;
            __builtin_amdgcn_global_load_lds(
                (const __attribute__((address_space(1))) void*)s,
                (__attribute__((address_space(3))) void*)&Abuf[buf][wbase * 8], 16, 0, 0);
        }
        #pragma unroll
        for (int p = 0; p < 2; ++p) {
            const int sidx = p * 256 + t;
            const int row  = sidx >> 2;
            const int ch   = sidx & 3;
            const _Float16* s = Wh16t + (size_t)(n0 + row) * DIM + k0 + ch * 8;
            __builtin_amdgcn_global_load_lds(
                (const __attribute__((address_space(1))) void*)s,
                (__attribute__((address_space(3))) void*)&Bbuf[buf][(p * 256 + wbase) * 8], 16, 0, 0);
        }
    };

    stage(0, 0);
    __syncthreads();

    for (int s = 0; s < 16; ++s) {
        const int buf = s & 1;
        if (s < 15) stage(buf ^ 1, (s + 1) * 32);

        half8 aF[4], bF[2];
        #pragma unroll
        for (int i = 0; i < 4; ++i)
            aF[i] = *(const half8*)&Abuf[buf][(16 * i + lm) * 32 + lq * 8];
        #pragma unroll
        for (int j = 0; j < 2; ++j)
            bF[j] = *(const half8*)&Bbuf[buf][(wn + 16 * j + lm) * 32 + lq * 8];

        #pragma unroll
        for (int i = 0; i < 4; ++i)
            #pragma unroll
            for (int j = 0; j < 2; ++j)
                acc[i][j] = __builtin_amdgcn_mfma_f32_16x16x32_f16(aF[i], bF[j], acc[i][j], 0, 0, 0);

        __syncthreads();
    }

    #pragma unroll
    for (int i = 0; i < 4; ++i)
        #pragma unroll
        for (int j = 0; j < 2; ++j)
            #pragma unroll
            for (int r = 0; r < 4; ++r) {
                const int gm = m0 + 16 * i + lq * 4 + r;
                const int gn = n0 + wn + 16 * j + lm;
                if (gm < NNODES)
                    ZWh[(size_t)gm * DIM + gn] = (_Float16)acc[i][j][r];
            }
}

// ---------------------------------------------------------------------------
// Counting sort of edges by row
// ---------------------------------------------------------------------------
__global__ void hist_rows(const int* __restrict__ eidx, int* __restrict__ counts) {
    int e = blockIdx.x * blockDim.x + threadIdx.x;
    if (e < NEDGES) atomicAdd(&counts[eidx[e]], 1);
}

__global__ __launch_bounds__(1024) void scan_counts(const int* __restrict__ counts,
                                                    int* __restrict__ offs,
                                                    int* __restrict__ cursor) {
    __shared__ int wsum[16];
    __shared__ int woff[17];
    const int t    = threadIdx.x;
    const int lane = t & 63;
    const int wv   = t >> 6;

    int local[10];
    int s = 0;
    if (t < 1000) {
        #pragma unroll
        for (int j = 0; j < 10; ++j) {
            local[j] = counts[t * 10 + j];
            s += local[j];
        }
    }
    int v = s;
    #pragma unroll
    for (int off = 1; off < 64; off <<= 1) {
        int u = __shfl_up(v, off, 64);
        if (lane >= off) v += u;
    }
    if (lane == 63) wsum[wv] = v;
    __syncthreads();
    if (t == 0) {
        int r = 0;
        #pragma unroll
        for (int i = 0; i < 16; ++i) { woff[i] = r; r += wsum[i]; }
        woff[16] = r;
    }
    __syncthreads();
    if (t < 1000) {
        int run = woff[wv] + (v - s);
        #pragma unroll
        for (int j = 0; j < 10; ++j) {
            offs[t * 10 + j]   = run;
            cursor[t * 10 + j] = run;
            run += local[j];
        }
    }
    if (t == 0) offs[NNODES] = woff[16];
}

__global__ void scatter_edges(const int* __restrict__ eidx,
                              int* __restrict__ cursor,
                              unsigned* __restrict__ keys) {
    int e = blockIdx.x * blockDim.x + threadIdx.x;
    if (e < NEDGES) {
        int r = eidx[e];
        int c = eidx[NEDGES + e];
        int pos = atomicAdd(&cursor[r], 1);
        keys[pos] = ((unsigned)c << 18) | (unsigned)e;
    }
}

// ---------------------------------------------------------------------------
// Edge scoring v4: 16 lanes per edge, 4 edges per wave in parallel.
// Block = 256 threads = 4 waves; wave w of block b handles row 4b+w.
// Lane sl (0..15) of group g covers 64 consecutive bytes of the row/col.
// One xor-mask shuffle reduction (1,2,4,8) reduces all 4 edges at once.
// fp16 dot2 accumulate into fp32.
// ---------------------------------------------------------------------------
__global__ __launch_bounds__(256) void edge_score_q(const _Float16* __restrict__ ZWh,
                                                    const _Float16* __restrict__ Zh,
                                                    const unsigned* __restrict__ keys,
                                                    const int* __restrict__ offs,
                                                    float* __restrict__ out) {
    const int r = blockIdx.x * 4 + (threadIdx.x >> 6);
    const int start = offs[r];
    const int end   = offs[r + 1];
    if (start == end) return;

    const int lane = threadIdx.x & 63;
    const int g    = lane >> 4;     // edge group 0..3
    const int sl   = lane & 15;     // sub-lane within group

    // row fragment: 32 consecutive halves (64 B) per lane
    const _Float16* rp = ZWh + (size_t)r * DIM + sl * 32;
    half8 ra0 = *(const half8*)(rp);
    half8 ra1 = *(const half8*)(rp + 8);
    half8 ra2 = *(const half8*)(rp + 16);
    half8 ra3 = *(const half8*)(rp + 24);

    for (int i = start; i < end; i += 4) {
        const int ii = i + g;
        const unsigned k = keys[ii < end ? ii : (end - 1)];
        const int c = (int)(k >> 18);

        const _Float16* cp = Zh + (size_t)c * DIM + sl * 32;
        half8 c0 = *(const half8*)(cp);
        half8 c1 = *(const half8*)(cp + 8);
        half8 c2 = *(const half8*)(cp + 16);
        half8 c3 = *(const half8*)(cp + 24);

        float s = 0.f;
        #pragma unroll
        for (int d = 0; d < 4; ++d) {
            s = dot2acc((half2v){ra0[2*d], ra0[2*d+1]}, (half2v){c0[2*d], c0[2*d+1]}, s);
            s = dot2acc((half2v){ra1[2*d], ra1[2*d+1]}, (half2v){c1[2*d], c1[2*d+1]}, s);
            s = dot2acc((half2v){ra2[2*d], ra2[2*d+1]}, (half2v){c2[2*d], c2[2*d+1]}, s);
            s = dot2acc((half2v){ra3[2*d], ra3[2*d+1]}, (half2v){c3[2*d], c3[2*d+1]}, s);
        }

        // reduce within each 16-lane group (all 4 edges simultaneously)
        s += __shfl_xor(s, 1, 64);
        s += __shfl_xor(s, 2, 64);
        s += __shfl_xor(s, 4, 64);
        s += __shfl_xor(s, 8, 64);

        if (sl == 0 && ii < end)
            out[k & 0x3FFFFu] = 1.0f / (1.0f + expf(-s));
    }
}

// ---------------------------------------------------------------------------
// fp32 fallback path (ws too small)
// ---------------------------------------------------------------------------
#define GTM 128
#define GTN 64
#define GTK 16
#define LDA 132
#define LDB 68

__global__ __launch_bounds__(256) void gemm_zw(const float* __restrict__ A,
                                               const float* __restrict__ B,
                                               float* __restrict__ C) {
    __shared__ float As[GTK * LDA];
    __shared__ float Bs[GTK * LDB];

    const int t  = threadIdx.x;
    const int m0 = blockIdx.x * GTM;
    const int n0 = blockIdx.y * GTN;
    const int tx = t & 15;
    const int ty = t >> 4;

    float acc[8][4] = {};

    for (int k0 = 0; k0 < DIM; k0 += GTK) {
        #pragma unroll
        for (int p = 0; p < 2; ++p) {
            int f  = t + p * 256;
            int mm = f >> 2;
            int kq = f & 3;
            int m  = m0 + mm;
            float4 v = make_float4(0.f, 0.f, 0.f, 0.f);
            if (m < NNODES)
                v = *(const float4*)(A + (size_t)m * DIM + k0 + kq * 4);
            As[(kq * 4 + 0) * LDA + mm] = v.x;
            As[(kq * 4 + 1) * LDA + mm] = v.y;
            As[(kq * 4 + 2) * LDA + mm] = v.z;
            As[(kq * 4 + 3) * LDA + mm] = v.w;
        }
        {
            int kb = t >> 4, n4 = t & 15;
            *(float4*)&Bs[kb * LDB + n4 * 4] =
                *(const float4*)(B + (size_t)(k0 + kb) * DIM + n0 + n4 * 4);
        }
        __syncthreads();

        #pragma unroll
        for (int kk = 0; kk < GTK; ++kk) {
            float4 a0 = *(const float4*)&As[kk * LDA + ty * 8];
            float4 a1 = *(const float4*)&As[kk * LDA + ty * 8 + 4];
            float4 b  = *(const float4*)&Bs[kk * LDB + tx * 4];
            float av[8] = {a0.x, a0.y, a0.z, a0.w, a1.x, a1.y, a1.z, a1.w};
            float bv[4] = {b.x, b.y, b.z, b.w};
            #pragma unroll
            for (int i = 0; i < 8; ++i)
                #pragma unroll
                for (int j = 0; j < 4; ++j)
                    acc[i][j] = fmaf(av[i], bv[j], acc[i][j]);
        }
        __syncthreads();
    }

    #pragma unroll
    for (int i = 0; i < 8; ++i) {
        int m = m0 + ty * 8 + i;
        if (m < NNODES)
            *(float4*)(C + (size_t)m * DIM + n0 + tx * 4) =
                make_float4(acc[i][0], acc[i][1], acc[i][2], acc[i][3]);
    }
}

__global__ __launch_bounds__(256) void edge_score(const float* __restrict__ ZW,
                                                  const float* __restrict__ Z,
                                                  const int* __restrict__ eidx,
                                                  float* __restrict__ out) {
    const int e    = blockIdx.x * 4 + (threadIdx.x >> 6);
    const int lane = threadIdx.x & 63;

    const int r = eidx[e];
    const int c = eidx[NEDGES + e];

    const float4* pr = (const float4*)(ZW + (size_t)r * DIM);
    const float4* pc = (const float4*)(Z  + (size_t)c * DIM);

    float4 a0 = pr[lane * 2 + 0];
    float4 a1 = pr[lane * 2 + 1];
    float4 b0 = pc[lane * 2 + 0];
    float4 b1 = pc[lane * 2 + 1];

    float s = a0.x * b0.x;
    s = fmaf(a0.y, b0.y, s);
    s = fmaf(a0.z, b0.z, s);
    s = fmaf(a0.w, b0.w, s);
    s = fmaf(a1.x, b1.x, s);
    s = fmaf(a1.y, b1.y, s);
    s = fmaf(a1.z, b1.z, s);
    s = fmaf(a1.w, b1.w, s);

    #pragma unroll
    for (int off = 32; off > 0; off >>= 1)
        s += __shfl_xor(s, off, 64);

    if (lane == 0)
        out[e] = 1.0f / (1.0f + expf(-s));
}

// ---------------------------------------------------------------------------
extern "C" void kernel_launch(void* const* d_in, const int* in_sizes, int n_in,
                              void* d_out, int out_size, void* d_ws, size_t ws_size,
                              hipStream_t stream) {
    const float* Z  = (const float*)d_in[0];
    const float* W  = (const float*)d_in[1];
    const int*   EI = (const int*)d_in[2];
    float* out = (float*)d_out;

    char* p = (char*)d_ws;
    _Float16* ZWh   = (_Float16*)p;  p += (size_t)MPAD * DIM * 2;
    _Float16* Zh16  = (_Float16*)p;  p += (size_t)MPAD * DIM * 2;
    _Float16* Wh16t = (_Float16*)p;  p += (size_t)DIM * DIM * 2;
    int* counts = (int*)p;           p += (size_t)NNODES * 4;
    int* offs   = (int*)p;           p += (size_t)(NNODES + 1) * 4;
    int* cursor = (int*)p;           p += (size_t)NNODES * 4;
    unsigned* keys = (unsigned*)p;   p += (size_t)NEDGES * 4;
    const size_t need_full = (size_t)(p - (char*)d_ws);

    if (ws_size >= need_full) {
        prep<<<PREP_ZBLK + 64, 256, 0, stream>>>(Z, W, Zh16, Wh16t, counts);
        gemm_f16<<<NMB * 4, 256, 0, stream>>>(Zh16, Wh16t, ZWh);
        hist_rows<<<(NEDGES + 255) / 256, 256, 0, stream>>>(EI, counts);
        scan_counts<<<1, 1024, 0, stream>>>(counts, offs, cursor);
        scatter_edges<<<(NEDGES + 255) / 256, 256, 0, stream>>>(EI, cursor, keys);
        edge_score_q<<<NNODES / 4, 256, 0, stream>>>(ZWh, Zh16, keys, offs, out);
    } else {
        float* ZW = (float*)d_ws;
        dim3 g1((NNODES + GTM - 1) / GTM, DIM / GTN);
        gemm_zw<<<g1, 256, 0, stream>>>(Z, W, ZW);
        edge_score<<<NEDGES / 4, 256, 0, stream>>>(ZW, Z, EI, out);
    }
}